// Round 1
// baseline (2581.358 us; speedup 1.0000x reference)
//
#include <hip/hip_runtime.h>

#define EPSBN 1e-5f

// ---------------------------------------------------------------- utilities
__global__ void k_fill(float* __restrict__ p, float v, int n) {
    int i = blockIdx.x * blockDim.x + threadIdx.x;
    if (i < n) p[i] = v;
}

__global__ void k_deg(const int* __restrict__ dst, float* __restrict__ deg, int E) {
    int i = blockIdx.x * blockDim.x + threadIdx.x;
    if (i < E) unsafeAtomicAdd(&deg[dst[i]], 1.0f);
}

__global__ void k_rsqrt(float* __restrict__ d, int n) {
    int i = blockIdx.x * blockDim.x + threadIdx.x;
    if (i < n) d[i] = rsqrtf(d[i]);
}

// --------------------------------------------------- linear + self-loop init
// h = X(N,K) @ W(K,64) ; agg = h * dis^2    (4 rows per 256-thread block)
// NOTE: for layers 1/2, agg aliases X. Safe: X rows are staged to LDS before
// any global write, and each block owns its 4 rows exclusively.
template <int K>
__launch_bounds__(256)
__global__ void k_linear(const float* __restrict__ X, const float* __restrict__ W,
                         const float* __restrict__ dis, float* __restrict__ h,
                         float* __restrict__ agg, int N) {
    __shared__ float Ws[K * 64];
    __shared__ float Xs[4][K];
    const int tid = threadIdx.x;
    for (int i = tid; i < K * 64; i += 256) Ws[i] = W[i];
    const int r0 = blockIdx.x * 4;
    if (tid < 4 * K) {
        int r = tid / K, c = tid - r * K;
        if (r0 + r < N) Xs[r][c] = X[(long)(r0 + r) * K + c];
    }
    __syncthreads();
    const int r4 = tid >> 6, c = tid & 63;
    const int row = r0 + r4;
    if (row >= N) return;
    float acc = 0.f;
#pragma unroll
    for (int k = 0; k < K; ++k) acc = fmaf(Xs[r4][k], Ws[k * 64 + c], acc);
    const float di = dis[row];
    h[(long)row * 64 + c] = acc;
    agg[(long)row * 64 + c] = acc * di * di;
}

// ------------------------------------------------------------- edge scatter
// one wave (64 lanes = 64 channels) per edge; 4 edges per block
__launch_bounds__(256)
__global__ void k_scatter(const int* __restrict__ src, const int* __restrict__ dst,
                          const float* __restrict__ dis, const float* __restrict__ h,
                          float* __restrict__ agg, int E) {
    const int e = blockIdx.x * 4 + (threadIdx.x >> 6);
    if (e >= E) return;
    const int lane = threadIdx.x & 63;
    const int s = src[e], d = dst[e];
    const float coef = dis[s] * dis[d];
    unsafeAtomicAdd(&agg[(long)d * 64 + lane], h[(long)s * 64 + lane] * coef);
}

// ------------------------------------------------------------------ BN stats
// st[0..63] = sum per channel, st[64..127] = sum of squares
__launch_bounds__(256)
__global__ void k_bnstats(const float* __restrict__ x, float* __restrict__ st, int N) {
    const int c = threadIdx.x & 63;
    const int rl = threadIdx.x >> 6;  // 0..3
    const int stride = gridDim.x * 4;
    float s = 0.f, s2 = 0.f;
    for (int r = blockIdx.x * 4 + rl; r < N; r += stride) {
        float v = x[(long)r * 64 + c];
        s += v;
        s2 = fmaf(v, v, s2);
    }
    __shared__ float ls[256], ls2[256];
    ls[threadIdx.x] = s;
    ls2[threadIdx.x] = s2;
    __syncthreads();
    if (threadIdx.x < 64) {
        s = ls[c] + ls[c + 64] + ls[c + 128] + ls[c + 192];
        s2 = ls2[c] + ls2[c + 64] + ls2[c + 128] + ls2[c + 192];
        unsafeAtomicAdd(&st[c], s);
        unsafeAtomicAdd(&st[64 + c], s2);
    }
}

// ------------------------------------------------------------- BN apply+ReLU
__launch_bounds__(256)
__global__ void k_bnapply(float* __restrict__ x, const float* __restrict__ st,
                          const float* __restrict__ g, const float* __restrict__ be,
                          int N) {
    const long i = (long)blockIdx.x * blockDim.x + threadIdx.x;
    if (i >= (long)N * 64) return;
    const int c = (int)(i & 63);
    const float inv = 1.0f / (float)N;
    const float m = st[c] * inv;
    const float v = st[64 + c] * inv - m * m;
    const float sc = g[c] * rsqrtf(v + EPSBN);
    const float sh = fmaf(-m, sc, be[c]);
    const float y = fmaf(x[i], sc, sh);
    x[i] = fmaxf(y, 0.f);
}

// ------------------------------------------------------------------- pooling
// batch is sorted: each wave owns a contiguous node range and flushes a
// register accumulator on graph-boundary -> few atomics.
__launch_bounds__(256)
__global__ void k_pool(const float* __restrict__ x, const int* __restrict__ batch,
                       float* __restrict__ poolsum, float* __restrict__ counts,
                       int N, int npw) {
    const int wid = (blockIdx.x * blockDim.x + threadIdx.x) >> 6;
    const int lane = threadIdx.x & 63;
    const int n0 = wid * npw;
    if (n0 >= N) return;
    const int n1 = min(n0 + npw, N);
    float acc = 0.f, cnt = 0.f;
    int g = batch[n0];
    for (int n = n0; n < n1; ++n) {
        int gn = batch[n];
        if (gn != g) {
            unsafeAtomicAdd(&poolsum[(long)g * 64 + lane], acc);
            if (lane == 0) unsafeAtomicAdd(&counts[g], cnt);
            acc = 0.f;
            cnt = 0.f;
            g = gn;
        }
        acc += x[(long)n * 64 + lane];
        cnt += 1.f;
    }
    unsafeAtomicAdd(&poolsum[(long)g * 64 + lane], acc);
    if (lane == 0) unsafeAtomicAdd(&counts[g], cnt);
}

// --------------------------------------------------------------------- heads
__launch_bounds__(256)
__global__ void k_heads(const float* __restrict__ poolsum, const float* __restrict__ counts,
                        const float* pW1, const float* pb1, const float* pW2, const float* pb2,
                        const float* aW1, const float* ab1, const float* aW2, const float* ab2,
                        const float* tW1, const float* tb1, const float* tW2, const float* tb2,
                        float* __restrict__ out, int G) {
    __shared__ float P[64 * 64];
    __shared__ float Hd[64 * 32];
    const int tid = threadIdx.x;
    for (int i = tid; i < G * 64; i += 256) {
        int g = i >> 6;
        P[i] = poolsum[i] / fmaxf(counts[g], 1.f);
    }
    __syncthreads();
    for (int j = 0; j < 3; ++j) {
        const float* W1 = (j == 0) ? pW1 : (j == 1) ? aW1 : tW1;
        const float* b1 = (j == 0) ? pb1 : (j == 1) ? ab1 : tb1;
        const float* W2 = (j == 0) ? pW2 : (j == 1) ? aW2 : tW2;
        const float* b2 = (j == 0) ? pb2 : (j == 1) ? ab2 : tb2;
        for (int i = tid; i < G * 32; i += 256) {
            int g = i >> 5, k = i & 31;
            float a = b1[k];
#pragma unroll
            for (int c = 0; c < 64; ++c) a = fmaf(P[g * 64 + c], W1[c * 32 + k], a);
            Hd[i] = fmaxf(a, 0.f);
        }
        __syncthreads();
        const int ow = (j == 2) ? 2 : 1;
        const int off = (j == 2) ? 2 : j;
        for (int i = tid; i < G * ow; i += 256) {
            int g = i / ow, o = i - g * ow;
            float a = b2[o];
#pragma unroll
            for (int k = 0; k < 32; ++k) a = fmaf(Hd[g * 32 + k], W2[k * ow + o], a);
            out[g * 4 + off + o] = a;
        }
        __syncthreads();
    }
}

// ====================================================================== host
extern "C" void kernel_launch(void* const* d_in, const int* in_sizes, int n_in,
                              void* d_out, int out_size, void* d_ws, size_t ws_size,
                              hipStream_t stream) {
    const int N = in_sizes[2];      // batch has N entries
    const int E = in_sizes[1] / 2;  // edge_index is [2, E]
    const int G = out_size / 4;     // output [G, 4]

    const float* x0 = (const float*)d_in[0];
    const int* ei = (const int*)d_in[1];
    const int* src = ei;
    const int* dst = ei + E;
    const int* batch = (const int*)d_in[2];

    const float* W[3] = {(const float*)d_in[3], (const float*)d_in[7], (const float*)d_in[11]};
    const float* gam[3] = {(const float*)d_in[5], (const float*)d_in[9], (const float*)d_in[13]};
    const float* bet[3] = {(const float*)d_in[6], (const float*)d_in[10], (const float*)d_in[14]};

    const float* pW1 = (const float*)d_in[15];
    const float* pb1 = (const float*)d_in[16];
    const float* pW2 = (const float*)d_in[17];
    const float* pb2 = (const float*)d_in[18];
    const float* aW1 = (const float*)d_in[19];
    const float* ab1 = (const float*)d_in[20];
    const float* aW2 = (const float*)d_in[21];
    const float* ab2 = (const float*)d_in[22];
    const float* tW1 = (const float*)d_in[23];
    const float* tb1 = (const float*)d_in[24];
    const float* tW2 = (const float*)d_in[25];
    const float* tb2 = (const float*)d_in[26];

    // ---- workspace carve (256B aligned)
    auto align = [](size_t x) { return (x + 255) & ~(size_t)255; };
    char* w = (char*)d_ws;
    float* dis = (float*)w;      w += align((size_t)N * 4);
    float* bufA = (float*)w;     w += align((size_t)N * 64 * 4);
    float* bufB = (float*)w;     w += align((size_t)N * 64 * 4);
    float* st = (float*)w;       w += align(128 * 4);
    float* poolsum = (float*)w;  w += align((size_t)G * 64 * 4);
    float* counts = (float*)w;   w += align((size_t)G * 4);
    (void)ws_size;

    // ---- degrees: deg = in-degree + 1 ; dis = rsqrt(deg)
    k_fill<<<(N + 255) / 256, 256, 0, stream>>>(dis, 1.0f, N);
    k_deg<<<(E + 255) / 256, 256, 0, stream>>>(dst, dis, E);
    k_rsqrt<<<(N + 255) / 256, 256, 0, stream>>>(dis, N);

    const int nb_lin = (N + 3) / 4;
    const int nb_sc = (E + 3) / 4;
    const int nb_el = (int)(((long)N * 64 + 255) / 256);

    // ---- layer 0 (K=3): input from d_in, agg into bufA
    k_linear<3><<<nb_lin, 256, 0, stream>>>(x0, W[0], dis, bufB, bufA, N);
    k_scatter<<<nb_sc, 256, 0, stream>>>(src, dst, dis, bufB, bufA, E);
    k_fill<<<1, 128, 0, stream>>>(st, 0.f, 128);
    k_bnstats<<<512, 256, 0, stream>>>(bufA, st, N);
    k_bnapply<<<nb_el, 256, 0, stream>>>(bufA, st, gam[0], bet[0], N);

    // ---- layers 1,2 (K=64): input bufA, h->bufB, agg overwrites bufA in place
    for (int l = 1; l < 3; ++l) {
        k_linear<64><<<nb_lin, 256, 0, stream>>>(bufA, W[l], dis, bufB, bufA, N);
        k_scatter<<<nb_sc, 256, 0, stream>>>(src, dst, dis, bufB, bufA, E);
        k_fill<<<1, 128, 0, stream>>>(st, 0.f, 128);
        k_bnstats<<<512, 256, 0, stream>>>(bufA, st, N);
        k_bnapply<<<nb_el, 256, 0, stream>>>(bufA, st, gam[l], bet[l], N);
    }

    // ---- global mean pool
    k_fill<<<(G * 64 + 255) / 256, 256, 0, stream>>>(poolsum, 0.f, G * 64);
    k_fill<<<1, 64, 0, stream>>>(counts, 0.f, G);
    const int npw = 256;  // nodes per wave
    const int nwaves = (N + npw - 1) / npw;
    const int nb_pool = (nwaves * 64 + 255) / 256;
    k_pool<<<nb_pool, 256, 0, stream>>>(bufA, batch, poolsum, counts, N, npw);

    // ---- heads
    k_heads<<<1, 256, 0, stream>>>(poolsum, counts, pW1, pb1, pW2, pb2,
                                   aW1, ab1, aW2, ab2, tW1, tb1, tW2, tb2,
                                   (float*)d_out, G);
}

// Round 2
// 1281.576 us; speedup vs baseline: 2.0142x; 2.0142x over previous
//
#include <hip/hip_runtime.h>

#define EPSBN 1e-5f

// ---------------------------------------------------------------- utilities
__global__ void k_fill(float* __restrict__ p, float v, int n) {
    int i = blockIdx.x * blockDim.x + threadIdx.x;
    if (i < n) p[i] = v;
}

__global__ void k_fill_i(int* __restrict__ p, int v, int n) {
    int i = blockIdx.x * blockDim.x + threadIdx.x;
    if (i < n) p[i] = v;
}

__global__ void k_copy_i(const int* __restrict__ a, int* __restrict__ b, int n) {
    int i = blockIdx.x * blockDim.x + threadIdx.x;
    if (i < n) b[i] = a[i];
}

// ------------------------------------------------------------------ CSR build
__global__ void k_count(const int* __restrict__ dst, int* __restrict__ cnt, int E) {
    int i = blockIdx.x * blockDim.x + threadIdx.x;
    if (i < E) atomicAdd(&cnt[dst[i]], 1);
}

// dis = rsqrt(in_degree + 1)
__global__ void k_dis(const int* __restrict__ cnt, float* __restrict__ dis, int N) {
    int i = blockIdx.x * blockDim.x + threadIdx.x;
    if (i < N) dis[i] = rsqrtf((float)cnt[i] + 1.0f);
}

// exclusive prefix sum of cnt -> off[0..N], single block of 1024 threads
__global__ void k_scan(const int* __restrict__ cnt, int* __restrict__ off, int N) {
    __shared__ int part[1024];
    const int t = threadIdx.x;
    const int chunk = (N + 1023) >> 10;
    const int lo = t * chunk, hi = min(lo + chunk, N);
    int s = 0;
    for (int i = lo; i < hi; ++i) s += cnt[i];
    part[t] = s;
    __syncthreads();
    for (int d = 1; d < 1024; d <<= 1) {
        int v = (t >= d) ? part[t - d] : 0;
        __syncthreads();
        part[t] += v;
        __syncthreads();
    }
    int run = (t == 0) ? 0 : part[t - 1];
    for (int i = lo; i < hi; ++i) {
        off[i] = run;
        run += cnt[i];
    }
    if (lo < N && hi == N) off[N] = run;
}

// edge data: (src, coef) packed per edge, grouped by dst
__global__ void k_fillcsr(const int* __restrict__ src, const int* __restrict__ dst,
                          const float* __restrict__ dis, int* __restrict__ cursor,
                          int2* __restrict__ eda, int E) {
    int e = blockIdx.x * blockDim.x + threadIdx.x;
    if (e >= E) return;
    const int s = src[e], d = dst[e];
    const int pos = atomicAdd(&cursor[d], 1);
    int2 v;
    v.x = s;
    v.y = __float_as_int(dis[s] * dis[d]);
    eda[pos] = v;
}

// --------------------------------------------------- fused (BN+ReLU) + linear
// h = act(X)(N,K) @ W(K,64); act = BN(st,g,be)+ReLU when BN=true, identity else.
// 32 rows per 256-thread block; W staged once per block.
template <int K, bool BN>
__launch_bounds__(256)
__global__ void k_linear(const float* __restrict__ X, const float* __restrict__ W,
                         const float* __restrict__ st, const float* __restrict__ g,
                         const float* __restrict__ be, float* __restrict__ h, int N) {
    __shared__ float Ws[K * 64];
    __shared__ float Xs[32 * K];
    __shared__ float scs[64], shs[64];
    const int tid = threadIdx.x;
    if (BN && tid < K) {
        const float inv = 1.0f / (float)N;
        const float m = st[tid] * inv;
        const float v = st[64 + tid] * inv - m * m;
        const float sc = g[tid] * rsqrtf(v + EPSBN);
        scs[tid] = sc;
        shs[tid] = fmaf(-m, sc, be[tid]);
    }
    for (int i = tid; i < K * 64; i += 256) Ws[i] = W[i];
    if (BN) __syncthreads();  // scs/shs ready before staging
    const int r0 = blockIdx.x * 32;
    for (int i = tid; i < 32 * K; i += 256) {
        const int r = i / K, c = i - r * K;
        const int row = r0 + r;
        float val = (row < N) ? X[(long)row * K + c] : 0.f;
        if (BN) val = fmaxf(fmaf(val, scs[c], shs[c]), 0.f);
        Xs[i] = val;
    }
    __syncthreads();
    const int c = tid & 63, wv = tid >> 6;
    for (int rr = 0; rr < 8; ++rr) {
        const int r = wv * 8 + rr;
        const int row = r0 + r;
        if (row >= N) break;
        float acc = 0.f;
#pragma unroll
        for (int k = 0; k < K; ++k) acc = fmaf(Xs[r * K + k], Ws[k * 64 + c], acc);
        h[(long)row * 64 + c] = acc;
    }
}

// ------------------------------------------------- CSR segmented aggregation
// one wave per dst node; agg[n] = h[n]*dis[n]^2 + sum_{e in CSR[n]} h[src]*coef
__launch_bounds__(256)
__global__ void k_gather(const int* __restrict__ off, const int2* __restrict__ eda,
                         const float* __restrict__ dis, const float* __restrict__ h,
                         float* __restrict__ agg, int N) {
    const int w = (blockIdx.x * blockDim.x + threadIdx.x) >> 6;
    const int lane = threadIdx.x & 63;
    if (w >= N) return;
    const int e0 = off[w], e1 = off[w + 1];
    const float di = dis[w];
    float acc = h[(long)w * 64 + lane] * di * di;
    for (int eb = e0; eb < e1; eb += 64) {
        const int m = min(64, e1 - eb);
        int2 ed = (eb + lane < e1) ? eda[eb + lane] : make_int2(0, 0);
        for (int j = 0; j < m; ++j) {
            const int s = __shfl(ed.x, j);
            const float cf = __int_as_float(__shfl(ed.y, j));
            acc = fmaf(h[(long)s * 64 + lane], cf, acc);
        }
    }
    agg[(long)w * 64 + lane] = acc;
}

// ------------------------------------------------------------------ BN stats
__launch_bounds__(256)
__global__ void k_bnstats(const float* __restrict__ x, float* __restrict__ st, int N) {
    const int c = threadIdx.x & 63;
    const int rl = threadIdx.x >> 6;
    const int stride = gridDim.x * 4;
    float s = 0.f, s2 = 0.f;
    for (int r = blockIdx.x * 4 + rl; r < N; r += stride) {
        float v = x[(long)r * 64 + c];
        s += v;
        s2 = fmaf(v, v, s2);
    }
    __shared__ float ls[256], ls2[256];
    ls[threadIdx.x] = s;
    ls2[threadIdx.x] = s2;
    __syncthreads();
    if (threadIdx.x < 64) {
        s = ls[c] + ls[c + 64] + ls[c + 128] + ls[c + 192];
        s2 = ls2[c] + ls2[c + 64] + ls2[c + 128] + ls2[c + 192];
        unsafeAtomicAdd(&st[c], s);
        unsafeAtomicAdd(&st[64 + c], s2);
    }
}

// ----------------------------------------------------- pooling (fused BN+ReLU)
__launch_bounds__(256)
__global__ void k_pool(const float* __restrict__ x, const int* __restrict__ batch,
                       const float* __restrict__ st, const float* __restrict__ g,
                       const float* __restrict__ be, float* __restrict__ poolsum,
                       float* __restrict__ counts, int N, int npw) {
    const int wid = (blockIdx.x * blockDim.x + threadIdx.x) >> 6;
    const int lane = threadIdx.x & 63;
    const int n0 = wid * npw;
    if (n0 >= N) return;
    const float inv = 1.0f / (float)N;
    const float m = st[lane] * inv;
    const float v = st[64 + lane] * inv - m * m;
    const float sc = g[lane] * rsqrtf(v + EPSBN);
    const float sh = fmaf(-m, sc, be[lane]);
    const int n1 = min(n0 + npw, N);
    float acc = 0.f, cnt = 0.f;
    int gr = batch[n0];
    for (int n = n0; n < n1; ++n) {
        int gn = batch[n];
        if (gn != gr) {
            unsafeAtomicAdd(&poolsum[(long)gr * 64 + lane], acc);
            if (lane == 0) unsafeAtomicAdd(&counts[gr], cnt);
            acc = 0.f;
            cnt = 0.f;
            gr = gn;
        }
        acc += fmaxf(fmaf(x[(long)n * 64 + lane], sc, sh), 0.f);
        cnt += 1.f;
    }
    unsafeAtomicAdd(&poolsum[(long)gr * 64 + lane], acc);
    if (lane == 0) unsafeAtomicAdd(&counts[gr], cnt);
}

// --------------------------------------------------------------------- heads
__launch_bounds__(256)
__global__ void k_heads(const float* __restrict__ poolsum, const float* __restrict__ counts,
                        const float* pW1, const float* pb1, const float* pW2, const float* pb2,
                        const float* aW1, const float* ab1, const float* aW2, const float* ab2,
                        const float* tW1, const float* tb1, const float* tW2, const float* tb2,
                        float* __restrict__ out, int G) {
    __shared__ float P[64 * 64];
    __shared__ float Hd[64 * 32];
    const int tid = threadIdx.x;
    for (int i = tid; i < G * 64; i += 256) {
        int g = i >> 6;
        P[i] = poolsum[i] / fmaxf(counts[g], 1.f);
    }
    __syncthreads();
    for (int j = 0; j < 3; ++j) {
        const float* W1 = (j == 0) ? pW1 : (j == 1) ? aW1 : tW1;
        const float* b1 = (j == 0) ? pb1 : (j == 1) ? ab1 : tb1;
        const float* W2 = (j == 0) ? pW2 : (j == 1) ? aW2 : tW2;
        const float* b2 = (j == 0) ? pb2 : (j == 1) ? ab2 : tb2;
        for (int i = tid; i < G * 32; i += 256) {
            int g = i >> 5, k = i & 31;
            float a = b1[k];
#pragma unroll
            for (int c = 0; c < 64; ++c) a = fmaf(P[g * 64 + c], W1[c * 32 + k], a);
            Hd[i] = fmaxf(a, 0.f);
        }
        __syncthreads();
        const int ow = (j == 2) ? 2 : 1;
        const int off = (j == 2) ? 2 : j;
        for (int i = tid; i < G * ow; i += 256) {
            int g = i / ow, o = i - g * ow;
            float a = b2[o];
#pragma unroll
            for (int k = 0; k < 32; ++k) a = fmaf(Hd[g * 32 + k], W2[k * ow + o], a);
            out[g * 4 + off + o] = a;
        }
        __syncthreads();
    }
}

// ====================================================================== host
extern "C" void kernel_launch(void* const* d_in, const int* in_sizes, int n_in,
                              void* d_out, int out_size, void* d_ws, size_t ws_size,
                              hipStream_t stream) {
    const int N = in_sizes[2];      // batch has N entries
    const int E = in_sizes[1] / 2;  // edge_index is [2, E]
    const int G = out_size / 4;     // output [G, 4]

    const float* x0 = (const float*)d_in[0];
    const int* ei = (const int*)d_in[1];
    const int* src = ei;
    const int* dst = ei + E;
    const int* batch = (const int*)d_in[2];

    const float* W[3] = {(const float*)d_in[3], (const float*)d_in[7], (const float*)d_in[11]};
    const float* gam[3] = {(const float*)d_in[5], (const float*)d_in[9], (const float*)d_in[13]};
    const float* bet[3] = {(const float*)d_in[6], (const float*)d_in[10], (const float*)d_in[14]};

    const float* pW1 = (const float*)d_in[15];
    const float* pb1 = (const float*)d_in[16];
    const float* pW2 = (const float*)d_in[17];
    const float* pb2 = (const float*)d_in[18];
    const float* aW1 = (const float*)d_in[19];
    const float* ab1 = (const float*)d_in[20];
    const float* aW2 = (const float*)d_in[21];
    const float* ab2 = (const float*)d_in[22];
    const float* tW1 = (const float*)d_in[23];
    const float* tb1 = (const float*)d_in[24];
    const float* tW2 = (const float*)d_in[25];
    const float* tb2 = (const float*)d_in[26];

    // ---- workspace carve (256B aligned)
    auto align = [](size_t x) { return (x + 255) & ~(size_t)255; };
    char* w = (char*)d_ws;
    float* dis = (float*)w;      w += align((size_t)N * 4);
    float* bufA = (float*)w;     w += align((size_t)N * 64 * 4);
    float* bufB = (float*)w;     w += align((size_t)N * 64 * 4);
    float* st = (float*)w;       w += align(128 * 4);
    float* poolsum = (float*)w;  w += align((size_t)G * 64 * 4);
    float* counts = (float*)w;   w += align((size_t)G * 4);
    int* cnt = (int*)w;          w += align((size_t)N * 4);
    int* off = (int*)w;          w += align((size_t)(N + 1) * 4);
    int* cursor = (int*)w;       w += align((size_t)N * 4);
    int2* eda = (int2*)w;        w += align((size_t)E * 8);
    (void)ws_size;

    const int nbN = (N + 255) / 256;
    const int nbE = (E + 255) / 256;
    const int nb_lin = (N + 31) / 32;
    const int nb_wpn = (N + 3) / 4;  // wave-per-node kernels

    // ---- CSR build (per launch; deterministic-safe since fully recomputed)
    k_fill_i<<<nbN, 256, 0, stream>>>(cnt, 0, N);
    k_count<<<nbE, 256, 0, stream>>>(dst, cnt, E);
    k_dis<<<nbN, 256, 0, stream>>>(cnt, dis, N);
    k_scan<<<1, 1024, 0, stream>>>(cnt, off, N);
    k_copy_i<<<nbN, 256, 0, stream>>>(off, cursor, N);
    k_fillcsr<<<nbE, 256, 0, stream>>>(src, dst, dis, cursor, eda, E);

    // ---- layer 0 (K=3, no input BN)
    k_linear<3, false><<<nb_lin, 256, 0, stream>>>(x0, W[0], nullptr, nullptr, nullptr, bufB, N);
    k_gather<<<nb_wpn, 256, 0, stream>>>(off, eda, dis, bufB, bufA, N);
    k_fill<<<1, 128, 0, stream>>>(st, 0.f, 128);
    k_bnstats<<<512, 256, 0, stream>>>(bufA, st, N);

    // ---- layers 1,2 (K=64, BN of previous layer fused into staging)
    for (int l = 1; l < 3; ++l) {
        k_linear<64, true><<<nb_lin, 256, 0, stream>>>(bufA, W[l], st, gam[l - 1], bet[l - 1], bufB, N);
        k_gather<<<nb_wpn, 256, 0, stream>>>(off, eda, dis, bufB, bufA, N);
        k_fill<<<1, 128, 0, stream>>>(st, 0.f, 128);
        k_bnstats<<<512, 256, 0, stream>>>(bufA, st, N);
    }

    // ---- global mean pool (BN of layer 2 fused)
    k_fill<<<(G * 64 + 255) / 256, 256, 0, stream>>>(poolsum, 0.f, G * 64);
    k_fill<<<1, 64, 0, stream>>>(counts, 0.f, G);
    const int npw = 256;
    const int nwaves = (N + npw - 1) / npw;
    const int nb_pool = (nwaves * 64 + 255) / 256;
    k_pool<<<nb_pool, 256, 0, stream>>>(bufA, batch, st, gam[2], bet[2], poolsum, counts, N, npw);

    // ---- heads
    k_heads<<<1, 256, 0, stream>>>(poolsum, counts, pW1, pb1, pW2, pb2,
                                   aW1, ab1, aW2, ab2, tW1, tb1, tW2, tb2,
                                   (float*)d_out, G);
}

// Round 3
// 1104.490 us; speedup vs baseline: 2.3372x; 1.1603x over previous
//
#include <hip/hip_runtime.h>
#include <hip/hip_fp16.h>

#define EPSBN 1e-5f

// ---------------------------------------------------------------- utilities
__global__ void k_fill(float* __restrict__ p, float v, int n) {
    int i = blockIdx.x * blockDim.x + threadIdx.x;
    if (i < n) p[i] = v;
}

__global__ void k_fill_i(int* __restrict__ p, int v, int n) {
    int i = blockIdx.x * blockDim.x + threadIdx.x;
    if (i < n) p[i] = v;
}

__global__ void k_copy_i(const int* __restrict__ a, int* __restrict__ b, int n) {
    int i = blockIdx.x * blockDim.x + threadIdx.x;
    if (i < n) b[i] = a[i];
}

// ------------------------------------------------------------------ CSR build
__global__ void k_count(const int* __restrict__ dst, int* __restrict__ cnt, int E) {
    int i = blockIdx.x * blockDim.x + threadIdx.x;
    if (i < E) atomicAdd(&cnt[dst[i]], 1);
}

// dis = rsqrt(in_degree + 1)
__global__ void k_dis(const int* __restrict__ cnt, float* __restrict__ dis, int N) {
    int i = blockIdx.x * blockDim.x + threadIdx.x;
    if (i < N) dis[i] = rsqrtf((float)cnt[i] + 1.0f);
}

// exclusive prefix sum of cnt -> off[0..N], single block of 1024 threads
__global__ void k_scan(const int* __restrict__ cnt, int* __restrict__ off, int N) {
    __shared__ int part[1024];
    const int t = threadIdx.x;
    const int chunk = (N + 1023) >> 10;
    const int lo = t * chunk, hi = min(lo + chunk, N);
    int s = 0;
    for (int i = lo; i < hi; ++i) s += cnt[i];
    part[t] = s;
    __syncthreads();
    for (int d = 1; d < 1024; d <<= 1) {
        int v = (t >= d) ? part[t - d] : 0;
        __syncthreads();
        part[t] += v;
        __syncthreads();
    }
    int run = (t == 0) ? 0 : part[t - 1];
    for (int i = lo; i < hi; ++i) {
        off[i] = run;
        run += cnt[i];
    }
    if (lo < N && hi == N) off[N] = run;
}

// edge srcs grouped by dst (coef folded into hp, so only src needed)
__global__ void k_fillcsr(const int* __restrict__ src, const int* __restrict__ dst,
                          int* __restrict__ cursor, int* __restrict__ eda, int E) {
    int e = blockIdx.x * blockDim.x + threadIdx.x;
    if (e >= E) return;
    const int d = dst[e];
    const int pos = atomicAdd(&cursor[d], 1);
    eda[pos] = src[e];
}

// --------------------------------------------------- fused (BN+ReLU) + linear
// hp = (act(X)(N,K) @ W(K,64)) * dis[row]  stored fp16.
// act = BN(st,g,be)+ReLU when BN=true, identity else. 32 rows/block.
template <int K, bool BN>
__launch_bounds__(256)
__global__ void k_linear(const float* __restrict__ X, const float* __restrict__ W,
                         const float* __restrict__ st, const float* __restrict__ g,
                         const float* __restrict__ be, const float* __restrict__ dis,
                         __half* __restrict__ hp, int N) {
    __shared__ float Ws[K * 64];
    __shared__ float Xs[32 * K];
    __shared__ float scs[64], shs[64];
    const int tid = threadIdx.x;
    if (BN && tid < K) {
        const float inv = 1.0f / (float)N;
        const float m = st[tid] * inv;
        const float v = st[64 + tid] * inv - m * m;
        const float sc = g[tid] * rsqrtf(v + EPSBN);
        scs[tid] = sc;
        shs[tid] = fmaf(-m, sc, be[tid]);
    }
    for (int i = tid; i < K * 64; i += 256) Ws[i] = W[i];
    if (BN) __syncthreads();  // scs/shs ready before staging
    const int r0 = blockIdx.x * 32;
    for (int i = tid; i < 32 * K; i += 256) {
        const int r = i / K, c = i - r * K;
        const int row = r0 + r;
        float val = (row < N) ? X[(long)row * K + c] : 0.f;
        if (BN) val = fmaxf(fmaf(val, scs[c], shs[c]), 0.f);
        Xs[i] = val;
    }
    __syncthreads();
    const int c = tid & 63, wv = tid >> 6;
    for (int rr = 0; rr < 8; ++rr) {
        const int r = wv * 8 + rr;
        const int row = r0 + r;
        if (row >= N) break;
        float acc = 0.f;
#pragma unroll
        for (int k = 0; k < K; ++k) acc = fmaf(Xs[r * K + k], Ws[k * 64 + c], acc);
        hp[(long)row * 64 + c] = __float2half(acc * dis[row]);
    }
}

// ------------------------------------------- CSR aggregation + fused BN stats
// one wave per node (grid-stride): agg[n] = dis[n]*(hp[n] + sum hp[src])
// st[c]/st[64+c] accumulate per-channel sum / sum-of-squares of agg.
__launch_bounds__(256)
__global__ void k_gather(const int* __restrict__ off, const int* __restrict__ eda,
                         const float* __restrict__ dis, const __half* __restrict__ hp,
                         float* __restrict__ agg, float* __restrict__ st, int N) {
    __shared__ int els[4][64];
    __shared__ float ls[256], ls2[256];
    const int lane = threadIdx.x & 63;
    const int wv = threadIdx.x >> 6;
    const int nwaves = gridDim.x * 4;
    float s = 0.f, s2 = 0.f;
    for (int w = blockIdx.x * 4 + wv; w < N; w += nwaves) {
        const int e0 = off[w], e1 = off[w + 1];
        float acc0 = __half2float(hp[(long)w * 64 + lane]);
        float acc1 = 0.f;
        for (int eb = e0; eb < e1; eb += 64) {
            const int mm = min(64, e1 - eb);
            if (eb + lane < e1) els[wv][lane] = eda[eb + lane];
            int j = 0;
            for (; j + 4 <= mm; j += 4) {
                const int s0 = els[wv][j], s1 = els[wv][j + 1];
                const int s2i = els[wv][j + 2], s3 = els[wv][j + 3];
                const float v0 = __half2float(hp[(long)s0 * 64 + lane]);
                const float v1 = __half2float(hp[(long)s1 * 64 + lane]);
                const float v2 = __half2float(hp[(long)s2i * 64 + lane]);
                const float v3 = __half2float(hp[(long)s3 * 64 + lane]);
                acc0 += v0 + v2;
                acc1 += v1 + v3;
            }
            for (; j < mm; ++j) acc0 += __half2float(hp[(long)els[wv][j] * 64 + lane]);
        }
        const float out = dis[w] * (acc0 + acc1);
        agg[(long)w * 64 + lane] = out;
        s += out;
        s2 = fmaf(out, out, s2);
    }
    ls[threadIdx.x] = s;
    ls2[threadIdx.x] = s2;
    __syncthreads();
    if (threadIdx.x < 64) {
        s = ls[lane] + ls[lane + 64] + ls[lane + 128] + ls[lane + 192];
        s2 = ls2[lane] + ls2[lane + 64] + ls2[lane + 128] + ls2[lane + 192];
        unsafeAtomicAdd(&st[lane], s);
        unsafeAtomicAdd(&st[64 + lane], s2);
    }
}

// ----------------------------------------------------- pooling (fused BN+ReLU)
__launch_bounds__(256)
__global__ void k_pool(const float* __restrict__ x, const int* __restrict__ batch,
                       const float* __restrict__ st, const float* __restrict__ g,
                       const float* __restrict__ be, float* __restrict__ poolsum,
                       float* __restrict__ counts, int N, int npw) {
    const int wid = (blockIdx.x * blockDim.x + threadIdx.x) >> 6;
    const int lane = threadIdx.x & 63;
    const int n0 = wid * npw;
    if (n0 >= N) return;
    const float inv = 1.0f / (float)N;
    const float m = st[lane] * inv;
    const float v = st[64 + lane] * inv - m * m;
    const float sc = g[lane] * rsqrtf(v + EPSBN);
    const float sh = fmaf(-m, sc, be[lane]);
    const int n1 = min(n0 + npw, N);
    float acc = 0.f, cnt = 0.f;
    int gr = batch[n0];
    for (int n = n0; n < n1; ++n) {
        int gn = batch[n];
        if (gn != gr) {
            unsafeAtomicAdd(&poolsum[(long)gr * 64 + lane], acc);
            if (lane == 0) unsafeAtomicAdd(&counts[gr], cnt);
            acc = 0.f;
            cnt = 0.f;
            gr = gn;
        }
        acc += fmaxf(fmaf(x[(long)n * 64 + lane], sc, sh), 0.f);
        cnt += 1.f;
    }
    unsafeAtomicAdd(&poolsum[(long)gr * 64 + lane], acc);
    if (lane == 0) unsafeAtomicAdd(&counts[gr], cnt);
}

// --------------------------------------------------------------------- heads
__launch_bounds__(256)
__global__ void k_heads(const float* __restrict__ poolsum, const float* __restrict__ counts,
                        const float* pW1, const float* pb1, const float* pW2, const float* pb2,
                        const float* aW1, const float* ab1, const float* aW2, const float* ab2,
                        const float* tW1, const float* tb1, const float* tW2, const float* tb2,
                        float* __restrict__ out, int G) {
    __shared__ float P[64 * 64];
    __shared__ float Hd[64 * 32];
    const int tid = threadIdx.x;
    for (int i = tid; i < G * 64; i += 256) {
        int g = i >> 6;
        P[i] = poolsum[i] / fmaxf(counts[g], 1.f);
    }
    __syncthreads();
    for (int j = 0; j < 3; ++j) {
        const float* W1 = (j == 0) ? pW1 : (j == 1) ? aW1 : tW1;
        const float* b1 = (j == 0) ? pb1 : (j == 1) ? ab1 : tb1;
        const float* W2 = (j == 0) ? pW2 : (j == 1) ? aW2 : tW2;
        const float* b2 = (j == 0) ? pb2 : (j == 1) ? ab2 : tb2;
        for (int i = tid; i < G * 32; i += 256) {
            int g = i >> 5, k = i & 31;
            float a = b1[k];
#pragma unroll
            for (int c = 0; c < 64; ++c) a = fmaf(P[g * 64 + c], W1[c * 32 + k], a);
            Hd[i] = fmaxf(a, 0.f);
        }
        __syncthreads();
        const int ow = (j == 2) ? 2 : 1;
        const int off = (j == 2) ? 2 : j;
        for (int i = tid; i < G * ow; i += 256) {
            int g = i / ow, o = i - g * ow;
            float a = b2[o];
#pragma unroll
            for (int k = 0; k < 32; ++k) a = fmaf(Hd[g * 32 + k], W2[k * ow + o], a);
            out[g * 4 + off + o] = a;
        }
        __syncthreads();
    }
}

// ====================================================================== host
extern "C" void kernel_launch(void* const* d_in, const int* in_sizes, int n_in,
                              void* d_out, int out_size, void* d_ws, size_t ws_size,
                              hipStream_t stream) {
    const int N = in_sizes[2];      // batch has N entries
    const int E = in_sizes[1] / 2;  // edge_index is [2, E]
    const int G = out_size / 4;     // output [G, 4]

    const float* x0 = (const float*)d_in[0];
    const int* ei = (const int*)d_in[1];
    const int* src = ei;
    const int* dst = ei + E;
    const int* batch = (const int*)d_in[2];

    const float* W[3] = {(const float*)d_in[3], (const float*)d_in[7], (const float*)d_in[11]};
    const float* gam[3] = {(const float*)d_in[5], (const float*)d_in[9], (const float*)d_in[13]};
    const float* bet[3] = {(const float*)d_in[6], (const float*)d_in[10], (const float*)d_in[14]};

    const float* pW1 = (const float*)d_in[15];
    const float* pb1 = (const float*)d_in[16];
    const float* pW2 = (const float*)d_in[17];
    const float* pb2 = (const float*)d_in[18];
    const float* aW1 = (const float*)d_in[19];
    const float* ab1 = (const float*)d_in[20];
    const float* aW2 = (const float*)d_in[21];
    const float* ab2 = (const float*)d_in[22];
    const float* tW1 = (const float*)d_in[23];
    const float* tb1 = (const float*)d_in[24];
    const float* tW2 = (const float*)d_in[25];
    const float* tb2 = (const float*)d_in[26];

    // ---- workspace carve (256B aligned)
    auto align = [](size_t x) { return (x + 255) & ~(size_t)255; };
    char* w = (char*)d_ws;
    float* dis = (float*)w;      w += align((size_t)N * 4);
    float* bufA = (float*)w;     w += align((size_t)N * 64 * 4);   // fp32 agg
    __half* hp = (__half*)w;     w += align((size_t)N * 64 * 2);   // fp16 messages
    float* st = (float*)w;       w += align(3 * 128 * 4);          // st0,st1,st2
    float* poolsum = (float*)w;  w += align((size_t)G * 64 * 4);
    float* counts = (float*)w;   w += align((size_t)G * 4);
    int* cnt = (int*)w;          w += align((size_t)N * 4);
    int* off = (int*)w;          w += align((size_t)(N + 1) * 4);
    int* cursor = (int*)w;       w += align((size_t)N * 4);
    int* eda = (int*)w;          w += align((size_t)E * 4);
    (void)ws_size;

    const int nbN = (N + 255) / 256;
    const int nbE = (E + 255) / 256;
    const int nb_lin = (N + 31) / 32;
    const int nb_ga = 1024;  // grid-stride gather

    // ---- CSR build
    k_fill_i<<<nbN, 256, 0, stream>>>(cnt, 0, N);
    k_count<<<nbE, 256, 0, stream>>>(dst, cnt, E);
    k_dis<<<nbN, 256, 0, stream>>>(cnt, dis, N);
    k_scan<<<1, 1024, 0, stream>>>(cnt, off, N);
    k_copy_i<<<nbN, 256, 0, stream>>>(off, cursor, N);
    k_fillcsr<<<nbE, 256, 0, stream>>>(src, dst, cursor, eda, E);
    k_fill<<<2, 256, 0, stream>>>(st, 0.f, 3 * 128);

    // ---- layer 0 (K=3, no input BN)
    k_linear<3, false><<<nb_lin, 256, 0, stream>>>(x0, W[0], nullptr, nullptr, nullptr, dis, hp, N);
    k_gather<<<nb_ga, 256, 0, stream>>>(off, eda, dis, hp, bufA, st, N);

    // ---- layers 1,2 (K=64, BN of previous layer fused into staging)
    for (int l = 1; l < 3; ++l) {
        k_linear<64, true><<<nb_lin, 256, 0, stream>>>(bufA, W[l], st + (l - 1) * 128,
                                                       gam[l - 1], bet[l - 1], dis, hp, N);
        k_gather<<<nb_ga, 256, 0, stream>>>(off, eda, dis, hp, bufA, st + l * 128, N);
    }

    // ---- global mean pool (BN of layer 2 fused)
    k_fill<<<(G * 64 + 255) / 256, 256, 0, stream>>>(poolsum, 0.f, G * 64);
    k_fill<<<1, 64, 0, stream>>>(counts, 0.f, G);
    const int npw = 32;
    const int nwaves = (N + npw - 1) / npw;
    const int nb_pool = (nwaves * 64 + 255) / 256;
    k_pool<<<nb_pool, 256, 0, stream>>>(bufA, batch, st + 256, gam[2], bet[2],
                                        poolsum, counts, N, npw);

    // ---- heads
    k_heads<<<1, 256, 0, stream>>>(poolsum, counts, pW1, pb1, pW2, pb2,
                                   aW1, ab1, aW2, ab2, tW1, tb1, tW2, tb2,
                                   (float*)d_out, G);
}

// Round 4
// 878.568 us; speedup vs baseline: 2.9381x; 1.2571x over previous
//
#include <hip/hip_runtime.h>
#include <hip/hip_fp16.h>

#define EPSBN 1e-5f
#define SH 7        // bucket = dst >> SH  (128 nodes per bucket)
#define CHUNK 16384 // edges per sort chunk

// ---------------------------------------------------------------- utilities
__global__ void k_fill(float* __restrict__ p, float v, int n) {
    int i = blockIdx.x * blockDim.x + threadIdx.x;
    if (i < n) p[i] = v;
}

// ------------------------------------------------------- bucketed count sort
// S1: per-chunk histogram over coarse buckets, bucket-major output
__launch_bounds__(256)
__global__ void k_hist(const int* __restrict__ dst, int* __restrict__ hist,
                       int E, int C, int NB) {
    __shared__ int h[1024];
    const int tid = threadIdx.x, c = blockIdx.x;
    for (int i = tid; i < NB; i += 256) h[i] = 0;
    __syncthreads();
    const int e0 = c * CHUNK, e1 = min(e0 + CHUNK, E);
    for (int e = e0 + tid; e < e1; e += 256) atomicAdd(&h[dst[e] >> SH], 1);
    __syncthreads();
    for (int b = tid; b < NB; b += 256) hist[b * C + c] = h[b];
}

// S2: in-place exclusive scan of hist[NB*C]; also off[N] = E
__launch_bounds__(1024)
__global__ void k_scan2(int* __restrict__ hist, int* __restrict__ off,
                        int M, int E, int N) {
    __shared__ int part[1024];
    const int t = threadIdx.x;
    const int chunk = (M + 1023) >> 10;
    const int lo = t * chunk, hi = min(lo + chunk, M);
    int s = 0;
    for (int i = lo; i < hi; ++i) s += hist[i];
    part[t] = s;
    __syncthreads();
    for (int d = 1; d < 1024; d <<= 1) {
        int v = (t >= d) ? part[t - d] : 0;
        __syncthreads();
        part[t] += v;
        __syncthreads();
    }
    int run = (t == 0) ? 0 : part[t - 1];
    for (int i = lo; i < hi; ++i) {
        int v = hist[i];
        hist[i] = run;
        run += v;
    }
    if (t == 0) off[N] = E;
}

// S3: scatter edges into bucket-grouped order (LDS cursors per bucket)
__launch_bounds__(256)
__global__ void k_sort(const int* __restrict__ src, const int* __restrict__ dst,
                       const int* __restrict__ hist, int2* __restrict__ sorted,
                       int E, int C, int NB) {
    __shared__ int cur[1024];
    const int tid = threadIdx.x, c = blockIdx.x;
    for (int b = tid; b < NB; b += 256) cur[b] = hist[b * C + c];
    __syncthreads();
    const int e0 = c * CHUNK, e1 = min(e0 + CHUNK, E);
    for (int e = e0 + tid; e < e1; e += 256) {
        const int d = dst[e];
        const int pos = atomicAdd(&cur[d >> SH], 1);
        sorted[pos] = make_int2(src[e], d);
    }
}

// S4: one block per bucket -> per-node counts, off[], dis[], and final eda
__launch_bounds__(256)
__global__ void k_csr(const int2* __restrict__ sorted, const int* __restrict__ hist,
                      int* __restrict__ off, float* __restrict__ dis,
                      int* __restrict__ eda, int E, int C, int NB, int N) {
    __shared__ int cnt_l[128], scn[128];
    const int tid = threadIdx.x, b = blockIdx.x;
    const int node0 = b << SH;
    const int nloc = min(128, N - node0);
    const int ebeg = hist[b * C];
    const int eend = (b + 1 < NB) ? hist[(b + 1) * C] : E;
    if (tid < 128) cnt_l[tid] = 0;
    __syncthreads();
    for (int e = ebeg + tid; e < eend; e += 256) {
        int2 p = sorted[e];
        atomicAdd(&cnt_l[p.y & 127], 1);
    }
    __syncthreads();
    if (tid < 128) scn[tid] = cnt_l[tid];
    __syncthreads();
    for (int d = 1; d < 128; d <<= 1) {
        int v = 0;
        if (tid < 128 && tid >= d) v = scn[tid - d];
        __syncthreads();
        if (tid < 128) scn[tid] += v;
        __syncthreads();
    }
    if (tid < nloc) {
        const int excl = scn[tid] - cnt_l[tid];
        off[node0 + tid] = ebeg + excl;
        dis[node0 + tid] = rsqrtf((float)cnt_l[tid] + 1.0f);
    }
    __syncthreads();
    if (tid < 128) cnt_l[tid] = scn[tid] - cnt_l[tid];  // reuse as cursor
    __syncthreads();
    for (int e = ebeg + tid; e < eend; e += 256) {
        int2 p = sorted[e];
        const int r = atomicAdd(&cnt_l[p.y & 127], 1);
        eda[ebeg + r] = p.x;
    }
}

// --------------------------------------------------- fused (BN+ReLU) + linear
// hp = (act(X)(N,K) @ W(K,64)) * dis[row]  stored fp16.
template <int K, bool BN>
__launch_bounds__(256)
__global__ void k_linear(const float* __restrict__ X, const float* __restrict__ W,
                         const float* __restrict__ st, const float* __restrict__ g,
                         const float* __restrict__ be, const float* __restrict__ dis,
                         __half* __restrict__ hp, int N) {
    __shared__ float Ws[K * 64];
    __shared__ float Xs[32 * K];
    __shared__ float scs[64], shs[64];
    const int tid = threadIdx.x;
    if (BN && tid < K) {
        const float inv = 1.0f / (float)N;
        const float m = st[tid] * inv;
        const float v = st[64 + tid] * inv - m * m;
        const float sc = g[tid] * rsqrtf(v + EPSBN);
        scs[tid] = sc;
        shs[tid] = fmaf(-m, sc, be[tid]);
    }
    for (int i = tid; i < K * 64; i += 256) Ws[i] = W[i];
    if (BN) __syncthreads();
    const int r0 = blockIdx.x * 32;
    for (int i = tid; i < 32 * K; i += 256) {
        const int r = i / K, c = i - r * K;
        const int row = r0 + r;
        float val = (row < N) ? X[(long)row * K + c] : 0.f;
        if (BN) val = fmaxf(fmaf(val, scs[c], shs[c]), 0.f);
        Xs[i] = val;
    }
    __syncthreads();
    const int c = tid & 63, wv = tid >> 6;
    for (int rr = 0; rr < 8; ++rr) {
        const int r = wv * 8 + rr;
        const int row = r0 + r;
        if (row >= N) break;
        float acc = 0.f;
#pragma unroll
        for (int k = 0; k < K; ++k) acc = fmaf(Xs[r * K + k], Ws[k * 64 + c], acc);
        hp[(long)row * 64 + c] = __float2half(acc * dis[row]);
    }
}

// ------------------------------------------- CSR aggregation + fused BN stats
__launch_bounds__(256)
__global__ void k_gather(const int* __restrict__ off, const int* __restrict__ eda,
                         const float* __restrict__ dis, const __half* __restrict__ hp,
                         float* __restrict__ agg, float* __restrict__ st, int N) {
    __shared__ int els[4][64];
    __shared__ float ls[256], ls2[256];
    const int lane = threadIdx.x & 63;
    const int wv = threadIdx.x >> 6;
    const int nwaves = gridDim.x * 4;
    float s = 0.f, s2 = 0.f;
    for (int w = blockIdx.x * 4 + wv; w < N; w += nwaves) {
        const int e0 = off[w], e1 = off[w + 1];
        float acc0 = __half2float(hp[(long)w * 64 + lane]);
        float acc1 = 0.f;
        for (int eb = e0; eb < e1; eb += 64) {
            const int mm = min(64, e1 - eb);
            if (eb + lane < e1) els[wv][lane] = eda[eb + lane];
            int j = 0;
            for (; j + 4 <= mm; j += 4) {
                const int s0 = els[wv][j], s1 = els[wv][j + 1];
                const int s2i = els[wv][j + 2], s3 = els[wv][j + 3];
                const float v0 = __half2float(hp[(long)s0 * 64 + lane]);
                const float v1 = __half2float(hp[(long)s1 * 64 + lane]);
                const float v2 = __half2float(hp[(long)s2i * 64 + lane]);
                const float v3 = __half2float(hp[(long)s3 * 64 + lane]);
                acc0 += v0 + v2;
                acc1 += v1 + v3;
            }
            for (; j < mm; ++j) acc0 += __half2float(hp[(long)els[wv][j] * 64 + lane]);
        }
        const float out = dis[w] * (acc0 + acc1);
        agg[(long)w * 64 + lane] = out;
        s += out;
        s2 = fmaf(out, out, s2);
    }
    ls[threadIdx.x] = s;
    ls2[threadIdx.x] = s2;
    __syncthreads();
    if (threadIdx.x < 64) {
        s = ls[lane] + ls[lane + 64] + ls[lane + 128] + ls[lane + 192];
        s2 = ls2[lane] + ls2[lane + 64] + ls2[lane + 128] + ls2[lane + 192];
        unsafeAtomicAdd(&st[lane], s);
        unsafeAtomicAdd(&st[64 + lane], s2);
    }
}

// ----------------------------------------------------- pooling (fused BN+ReLU)
__launch_bounds__(256)
__global__ void k_pool(const float* __restrict__ x, const int* __restrict__ batch,
                       const float* __restrict__ st, const float* __restrict__ g,
                       const float* __restrict__ be, float* __restrict__ poolsum,
                       float* __restrict__ counts, int N, int npw) {
    const int wid = (blockIdx.x * blockDim.x + threadIdx.x) >> 6;
    const int lane = threadIdx.x & 63;
    const int n0 = wid * npw;
    if (n0 >= N) return;
    const float inv = 1.0f / (float)N;
    const float m = st[lane] * inv;
    const float v = st[64 + lane] * inv - m * m;
    const float sc = g[lane] * rsqrtf(v + EPSBN);
    const float sh = fmaf(-m, sc, be[lane]);
    const int n1 = min(n0 + npw, N);
    float acc = 0.f, cnt = 0.f;
    int gr = batch[n0];
    for (int n = n0; n < n1; ++n) {
        int gn = batch[n];
        if (gn != gr) {
            unsafeAtomicAdd(&poolsum[(long)gr * 64 + lane], acc);
            if (lane == 0) unsafeAtomicAdd(&counts[gr], cnt);
            acc = 0.f;
            cnt = 0.f;
            gr = gn;
        }
        acc += fmaxf(fmaf(x[(long)n * 64 + lane], sc, sh), 0.f);
        cnt += 1.f;
    }
    unsafeAtomicAdd(&poolsum[(long)gr * 64 + lane], acc);
    if (lane == 0) unsafeAtomicAdd(&counts[gr], cnt);
}

// --------------------------------------------------------------------- heads
__launch_bounds__(256)
__global__ void k_heads(const float* __restrict__ poolsum, const float* __restrict__ counts,
                        const float* pW1, const float* pb1, const float* pW2, const float* pb2,
                        const float* aW1, const float* ab1, const float* aW2, const float* ab2,
                        const float* tW1, const float* tb1, const float* tW2, const float* tb2,
                        float* __restrict__ out, int G) {
    __shared__ float P[64 * 64];
    __shared__ float Hd[64 * 32];
    const int tid = threadIdx.x;
    for (int i = tid; i < G * 64; i += 256) {
        int g = i >> 6;
        P[i] = poolsum[i] / fmaxf(counts[g], 1.f);
    }
    __syncthreads();
    for (int j = 0; j < 3; ++j) {
        const float* W1 = (j == 0) ? pW1 : (j == 1) ? aW1 : tW1;
        const float* b1 = (j == 0) ? pb1 : (j == 1) ? ab1 : tb1;
        const float* W2 = (j == 0) ? pW2 : (j == 1) ? aW2 : tW2;
        const float* b2 = (j == 0) ? pb2 : (j == 1) ? ab2 : tb2;
        for (int i = tid; i < G * 32; i += 256) {
            int g = i >> 5, k = i & 31;
            float a = b1[k];
#pragma unroll
            for (int c = 0; c < 64; ++c) a = fmaf(P[g * 64 + c], W1[c * 32 + k], a);
            Hd[i] = fmaxf(a, 0.f);
        }
        __syncthreads();
        const int ow = (j == 2) ? 2 : 1;
        const int off = (j == 2) ? 2 : j;
        for (int i = tid; i < G * ow; i += 256) {
            int g = i / ow, o = i - g * ow;
            float a = b2[o];
#pragma unroll
            for (int k = 0; k < 32; ++k) a = fmaf(Hd[g * 32 + k], W2[k * ow + o], a);
            out[g * 4 + off + o] = a;
        }
        __syncthreads();
    }
}

// ====================================================================== host
extern "C" void kernel_launch(void* const* d_in, const int* in_sizes, int n_in,
                              void* d_out, int out_size, void* d_ws, size_t ws_size,
                              hipStream_t stream) {
    const int N = in_sizes[2];      // batch has N entries
    const int E = in_sizes[1] / 2;  // edge_index is [2, E]
    const int G = out_size / 4;     // output [G, 4]

    const float* x0 = (const float*)d_in[0];
    const int* ei = (const int*)d_in[1];
    const int* src = ei;
    const int* dst = ei + E;
    const int* batch = (const int*)d_in[2];

    const float* W[3] = {(const float*)d_in[3], (const float*)d_in[7], (const float*)d_in[11]};
    const float* gam[3] = {(const float*)d_in[5], (const float*)d_in[9], (const float*)d_in[13]};
    const float* bet[3] = {(const float*)d_in[6], (const float*)d_in[10], (const float*)d_in[14]};

    const float* pW1 = (const float*)d_in[15];
    const float* pb1 = (const float*)d_in[16];
    const float* pW2 = (const float*)d_in[17];
    const float* pb2 = (const float*)d_in[18];
    const float* aW1 = (const float*)d_in[19];
    const float* ab1 = (const float*)d_in[20];
    const float* aW2 = (const float*)d_in[21];
    const float* ab2 = (const float*)d_in[22];
    const float* tW1 = (const float*)d_in[23];
    const float* tb1 = (const float*)d_in[24];
    const float* tW2 = (const float*)d_in[25];
    const float* tb2 = (const float*)d_in[26];

    const int C = (E + CHUNK - 1) / CHUNK;   // sort chunks
    const int NB = (N + 127) >> SH;          // coarse buckets (<=1024 for N<=128K)

    // ---- workspace carve (256B aligned)
    auto align = [](size_t x) { return (x + 255) & ~(size_t)255; };
    char* w = (char*)d_ws;
    float* dis = (float*)w;      w += align((size_t)N * 4);
    float* bufA = (float*)w;     w += align((size_t)N * 64 * 4);   // fp32 agg
    __half* hp = (__half*)w;     w += align((size_t)N * 64 * 2);   // fp16 messages
    float* st = (float*)w;       w += align(3 * 128 * 4);          // st0,st1,st2
    float* poolsum = (float*)w;  w += align((size_t)G * 64 * 4);
    float* counts = (float*)w;   w += align((size_t)G * 4);
    int* off = (int*)w;          w += align((size_t)(N + 1) * 4);
    int* hist = (int*)w;         w += align((size_t)NB * C * 4);
    int2* sorted = (int2*)w;     w += align((size_t)E * 8);
    int* eda = (int*)w;          w += align((size_t)E * 4);
    (void)ws_size;

    const int nb_lin = (N + 31) / 32;
    const int nb_ga = 1024;  // grid-stride gather

    // ---- CSR build via bucketed counting sort
    k_hist<<<C, 256, 0, stream>>>(dst, hist, E, C, NB);
    k_scan2<<<1, 1024, 0, stream>>>(hist, off, NB * C, E, N);
    k_sort<<<C, 256, 0, stream>>>(src, dst, hist, sorted, E, C, NB);
    k_csr<<<NB, 256, 0, stream>>>(sorted, hist, off, dis, eda, E, C, NB, N);
    k_fill<<<2, 256, 0, stream>>>(st, 0.f, 3 * 128);

    // ---- layer 0 (K=3, no input BN)
    k_linear<3, false><<<nb_lin, 256, 0, stream>>>(x0, W[0], nullptr, nullptr, nullptr, dis, hp, N);
    k_gather<<<nb_ga, 256, 0, stream>>>(off, eda, dis, hp, bufA, st, N);

    // ---- layers 1,2 (K=64, BN of previous layer fused into staging)
    for (int l = 1; l < 3; ++l) {
        k_linear<64, true><<<nb_lin, 256, 0, stream>>>(bufA, W[l], st + (l - 1) * 128,
                                                       gam[l - 1], bet[l - 1], dis, hp, N);
        k_gather<<<nb_ga, 256, 0, stream>>>(off, eda, dis, hp, bufA, st + l * 128, N);
    }

    // ---- global mean pool (BN of layer 2 fused)
    k_fill<<<(G * 64 + 255) / 256, 256, 0, stream>>>(poolsum, 0.f, G * 64);
    k_fill<<<1, 64, 0, stream>>>(counts, 0.f, G);
    const int npw = 32;
    const int nwaves = (N + npw - 1) / npw;
    const int nb_pool = (nwaves * 64 + 255) / 256;
    k_pool<<<nb_pool, 256, 0, stream>>>(bufA, batch, st + 256, gam[2], bet[2],
                                        poolsum, counts, N, npw);

    // ---- heads
    k_heads<<<1, 256, 0, stream>>>(poolsum, counts, pW1, pb1, pW2, pb2,
                                   aW1, ab1, aW2, ab2, tW1, tb1, tW2, tb2,
                                   (float*)d_out, G);
}

// Round 5
// 635.568 us; speedup vs baseline: 4.0615x; 1.3823x over previous
//
#include <hip/hip_runtime.h>
#include <hip/hip_fp16.h>

#define EPSBN 1e-5f
#define SH 7          // bucket = dst >> SH  (128 nodes per bucket)
#define CHUNK 16384   // edges per sort chunk
#define SCANB 256     // scan blocks

// ---------------------------------------------------------------- utilities
__global__ void k_fill(float* __restrict__ p, float v, int n) {
    int i = blockIdx.x * blockDim.x + threadIdx.x;
    if (i < n) p[i] = v;
}

// ------------------------------------------------------- bucketed count sort
// S1: per-chunk histogram over coarse buckets, bucket-major output
__launch_bounds__(256)
__global__ void k_hist(const int* __restrict__ dst, int* __restrict__ hist,
                       int E, int C, int NB) {
    __shared__ int h[1024];
    const int tid = threadIdx.x, c = blockIdx.x;
    for (int i = tid; i < NB; i += 256) h[i] = 0;
    __syncthreads();
    const int e0 = c * CHUNK, e1 = min(e0 + CHUNK, E);
    for (int e = e0 + tid; e < e1; e += 256) atomicAdd(&h[dst[e] >> SH], 1);
    __syncthreads();
    for (int b = tid; b < NB; b += 256) hist[b * C + c] = h[b];
}

// S2a: per-segment sums
__launch_bounds__(256)
__global__ void k_scanA(const int* __restrict__ hist, int* __restrict__ bsum, int M) {
    __shared__ int part[256];
    const int b = blockIdx.x, t = threadIdx.x;
    const int seg = (M + SCANB - 1) / SCANB;
    const int lo = b * seg, hi = min(lo + seg, M);
    int s = 0;
    for (int i = lo + t; i < hi; i += 256) s += hist[i];
    part[t] = s;
    __syncthreads();
    for (int d = 128; d > 0; d >>= 1) {
        if (t < d) part[t] += part[t + d];
        __syncthreads();
    }
    if (t == 0) bsum[b] = part[0];
}

// S2b: exclusive scan of bsum[SCANB], single block
__launch_bounds__(256)
__global__ void k_scanB(int* __restrict__ bsum) {
    __shared__ int sh[256];
    const int t = threadIdx.x;
    sh[t] = bsum[t];
    __syncthreads();
    for (int d = 1; d < 256; d <<= 1) {
        int v = (t >= d) ? sh[t - d] : 0;
        __syncthreads();
        sh[t] += v;
        __syncthreads();
    }
    bsum[t] = (t == 0) ? 0 : sh[t - 1];
}

// S2c: per-segment exclusive scan (in place) + bsum offset; off[N]=E
__launch_bounds__(256)
__global__ void k_scanC(int* __restrict__ hist, const int* __restrict__ bsum,
                        int* __restrict__ off, int M, int E, int N) {
    __shared__ int part[256];
    const int b = blockIdx.x, t = threadIdx.x;
    const int seg = (M + SCANB - 1) / SCANB;
    const int lo = b * seg, hi = min(lo + seg, M);
    const int per = (seg + 255) >> 8;
    const int tl = lo + t * per, th = min(tl + per, hi);
    int s = 0;
    for (int i = tl; i < th; ++i) s += hist[i];
    part[t] = s;
    __syncthreads();
    for (int d = 1; d < 256; d <<= 1) {
        int v = (t >= d) ? part[t - d] : 0;
        __syncthreads();
        part[t] += v;
        __syncthreads();
    }
    int run = bsum[b] + ((t == 0) ? 0 : part[t - 1]);
    for (int i = tl; i < th; ++i) {
        int v = hist[i];
        hist[i] = run;
        run += v;
    }
    if (b == 0 && t == 0) off[N] = E;
}

// S3: scatter edges into bucket-grouped order (LDS cursors per bucket)
__launch_bounds__(256)
__global__ void k_sort(const int* __restrict__ src, const int* __restrict__ dst,
                       const int* __restrict__ hist, int2* __restrict__ sorted,
                       int E, int C, int NB) {
    __shared__ int cur[1024];
    const int tid = threadIdx.x, c = blockIdx.x;
    for (int b = tid; b < NB; b += 256) cur[b] = hist[b * C + c];
    __syncthreads();
    const int e0 = c * CHUNK, e1 = min(e0 + CHUNK, E);
    for (int e = e0 + tid; e < e1; e += 256) {
        const int d = dst[e];
        const int pos = atomicAdd(&cur[d >> SH], 1);
        sorted[pos] = make_int2(src[e], d);
    }
}

// S4: one block per bucket -> per-node counts, off[], dis[], and final eda
__launch_bounds__(256)
__global__ void k_csr(const int2* __restrict__ sorted, const int* __restrict__ hist,
                      int* __restrict__ off, float* __restrict__ dis,
                      int* __restrict__ eda, int E, int C, int NB, int N) {
    __shared__ int cnt_l[128], scn[128];
    const int tid = threadIdx.x, b = blockIdx.x;
    const int node0 = b << SH;
    const int nloc = min(128, N - node0);
    const int ebeg = hist[b * C];
    const int eend = (b + 1 < NB) ? hist[(b + 1) * C] : E;
    if (tid < 128) cnt_l[tid] = 0;
    __syncthreads();
    for (int e = ebeg + tid; e < eend; e += 256) {
        int2 p = sorted[e];
        atomicAdd(&cnt_l[p.y & 127], 1);
    }
    __syncthreads();
    if (tid < 128) scn[tid] = cnt_l[tid];
    __syncthreads();
    for (int d = 1; d < 128; d <<= 1) {
        int v = 0;
        if (tid < 128 && tid >= d) v = scn[tid - d];
        __syncthreads();
        if (tid < 128) scn[tid] += v;
        __syncthreads();
    }
    if (tid < nloc) {
        const int excl = scn[tid] - cnt_l[tid];
        off[node0 + tid] = ebeg + excl;
        dis[node0 + tid] = rsqrtf((float)cnt_l[tid] + 1.0f);
    }
    __syncthreads();
    if (tid < 128) cnt_l[tid] = scn[tid] - cnt_l[tid];  // reuse as cursor
    __syncthreads();
    for (int e = ebeg + tid; e < eend; e += 256) {
        int2 p = sorted[e];
        const int r = atomicAdd(&cnt_l[p.y & 127], 1);
        eda[ebeg + r] = p.x;
    }
}

// --------------------------------------------------- fused (BN+ReLU) + linear
// hp = (act(X)(N,K) @ W(K,64)) * dis[row]  stored fp16.
template <int K, bool BN>
__launch_bounds__(256)
__global__ void k_linear(const float* __restrict__ X, const float* __restrict__ W,
                         const float* __restrict__ st, const float* __restrict__ g,
                         const float* __restrict__ be, const float* __restrict__ dis,
                         __half* __restrict__ hp, int N) {
    __shared__ float Ws[K * 64];
    __shared__ float Xs[32 * K];
    __shared__ float scs[64], shs[64];
    const int tid = threadIdx.x;
    if (BN && tid < K) {
        const float inv = 1.0f / (float)N;
        const float m = st[tid] * inv;
        const float v = st[64 + tid] * inv - m * m;
        const float sc = g[tid] * rsqrtf(v + EPSBN);
        scs[tid] = sc;
        shs[tid] = fmaf(-m, sc, be[tid]);
    }
    for (int i = tid; i < K * 64; i += 256) Ws[i] = W[i];
    if (BN) __syncthreads();
    const int r0 = blockIdx.x * 32;
    for (int i = tid; i < 32 * K; i += 256) {
        const int r = i / K, c = i - r * K;
        const int row = r0 + r;
        float val = (row < N) ? X[(long)row * K + c] : 0.f;
        if (BN) val = fmaxf(fmaf(val, scs[c], shs[c]), 0.f);
        Xs[i] = val;
    }
    __syncthreads();
    const int c = tid & 63, wv = tid >> 6;
    for (int rr = 0; rr < 8; ++rr) {
        const int r = wv * 8 + rr;
        const int row = r0 + r;
        if (row >= N) break;
        float acc = 0.f;
#pragma unroll
        for (int k = 0; k < K; ++k) acc = fmaf(Xs[r * K + k], Ws[k * 64 + c], acc);
        hp[(long)row * 64 + c] = __float2half(acc * dis[row]);
    }
}

// ------------------------------------------- CSR aggregation + fused BN stats
__launch_bounds__(256)
__global__ void k_gather(const int* __restrict__ off, const int* __restrict__ eda,
                         const float* __restrict__ dis, const __half* __restrict__ hp,
                         float* __restrict__ agg, float* __restrict__ st, int N) {
    __shared__ int els[4][64];
    __shared__ float ls[256], ls2[256];
    const int lane = threadIdx.x & 63;
    const int wv = threadIdx.x >> 6;
    const int nwaves = gridDim.x * 4;
    float s = 0.f, s2 = 0.f;
    for (int w = blockIdx.x * 4 + wv; w < N; w += nwaves) {
        const int e0 = off[w], e1 = off[w + 1];
        float acc0 = __half2float(hp[(long)w * 64 + lane]);
        float acc1 = 0.f;
        for (int eb = e0; eb < e1; eb += 64) {
            const int mm = min(64, e1 - eb);
            if (eb + lane < e1) els[wv][lane] = eda[eb + lane];
            int j = 0;
            for (; j + 4 <= mm; j += 4) {
                const int s0 = els[wv][j], s1 = els[wv][j + 1];
                const int s2i = els[wv][j + 2], s3 = els[wv][j + 3];
                const float v0 = __half2float(hp[(long)s0 * 64 + lane]);
                const float v1 = __half2float(hp[(long)s1 * 64 + lane]);
                const float v2 = __half2float(hp[(long)s2i * 64 + lane]);
                const float v3 = __half2float(hp[(long)s3 * 64 + lane]);
                acc0 += v0 + v2;
                acc1 += v1 + v3;
            }
            for (; j < mm; ++j) acc0 += __half2float(hp[(long)els[wv][j] * 64 + lane]);
        }
        const float out = dis[w] * (acc0 + acc1);
        agg[(long)w * 64 + lane] = out;
        s += out;
        s2 = fmaf(out, out, s2);
    }
    ls[threadIdx.x] = s;
    ls2[threadIdx.x] = s2;
    __syncthreads();
    if (threadIdx.x < 64) {
        s = ls[lane] + ls[lane + 64] + ls[lane + 128] + ls[lane + 192];
        s2 = ls2[lane] + ls2[lane + 64] + ls2[lane + 128] + ls2[lane + 192];
        unsafeAtomicAdd(&st[lane], s);
        unsafeAtomicAdd(&st[64 + lane], s2);
    }
}

// ----------------------------------------------------- pooling (fused BN+ReLU)
__launch_bounds__(256)
__global__ void k_pool(const float* __restrict__ x, const int* __restrict__ batch,
                       const float* __restrict__ st, const float* __restrict__ g,
                       const float* __restrict__ be, float* __restrict__ poolsum,
                       float* __restrict__ counts, int N, int npw) {
    const int wid = (blockIdx.x * blockDim.x + threadIdx.x) >> 6;
    const int lane = threadIdx.x & 63;
    const int n0 = wid * npw;
    if (n0 >= N) return;
    const float inv = 1.0f / (float)N;
    const float m = st[lane] * inv;
    const float v = st[64 + lane] * inv - m * m;
    const float sc = g[lane] * rsqrtf(v + EPSBN);
    const float sh = fmaf(-m, sc, be[lane]);
    const int n1 = min(n0 + npw, N);
    float acc = 0.f, cnt = 0.f;
    int gr = batch[n0];
    for (int n = n0; n < n1; ++n) {
        int gn = batch[n];
        if (gn != gr) {
            unsafeAtomicAdd(&poolsum[(long)gr * 64 + lane], acc);
            if (lane == 0) unsafeAtomicAdd(&counts[gr], cnt);
            acc = 0.f;
            cnt = 0.f;
            gr = gn;
        }
        acc += fmaxf(fmaf(x[(long)n * 64 + lane], sc, sh), 0.f);
        cnt += 1.f;
    }
    unsafeAtomicAdd(&poolsum[(long)gr * 64 + lane], acc);
    if (lane == 0) unsafeAtomicAdd(&counts[gr], cnt);
}

// --------------------------------------------------------------------- heads
__launch_bounds__(256)
__global__ void k_heads(const float* __restrict__ poolsum, const float* __restrict__ counts,
                        const float* pW1, const float* pb1, const float* pW2, const float* pb2,
                        const float* aW1, const float* ab1, const float* aW2, const float* ab2,
                        const float* tW1, const float* tb1, const float* tW2, const float* tb2,
                        float* __restrict__ out, int G) {
    __shared__ float P[64 * 64];
    __shared__ float Hd[64 * 32];
    const int tid = threadIdx.x;
    for (int i = tid; i < G * 64; i += 256) {
        int g = i >> 6;
        P[i] = poolsum[i] / fmaxf(counts[g], 1.f);
    }
    __syncthreads();
    for (int j = 0; j < 3; ++j) {
        const float* W1 = (j == 0) ? pW1 : (j == 1) ? aW1 : tW1;
        const float* b1 = (j == 0) ? pb1 : (j == 1) ? ab1 : tb1;
        const float* W2 = (j == 0) ? pW2 : (j == 1) ? aW2 : tW2;
        const float* b2 = (j == 0) ? pb2 : (j == 1) ? ab2 : tb2;
        for (int i = tid; i < G * 32; i += 256) {
            int g = i >> 5, k = i & 31;
            float a = b1[k];
#pragma unroll
            for (int c = 0; c < 64; ++c) a = fmaf(P[g * 64 + c], W1[c * 32 + k], a);
            Hd[i] = fmaxf(a, 0.f);
        }
        __syncthreads();
        const int ow = (j == 2) ? 2 : 1;
        const int off = (j == 2) ? 2 : j;
        for (int i = tid; i < G * ow; i += 256) {
            int g = i / ow, o = i - g * ow;
            float a = b2[o];
#pragma unroll
            for (int k = 0; k < 32; ++k) a = fmaf(Hd[g * 32 + k], W2[k * ow + o], a);
            out[g * 4 + off + o] = a;
        }
        __syncthreads();
    }
}

// ====================================================================== host
extern "C" void kernel_launch(void* const* d_in, const int* in_sizes, int n_in,
                              void* d_out, int out_size, void* d_ws, size_t ws_size,
                              hipStream_t stream) {
    const int N = in_sizes[2];      // batch has N entries
    const int E = in_sizes[1] / 2;  // edge_index is [2, E]
    const int G = out_size / 4;     // output [G, 4]

    const float* x0 = (const float*)d_in[0];
    const int* ei = (const int*)d_in[1];
    const int* src = ei;
    const int* dst = ei + E;
    const int* batch = (const int*)d_in[2];

    const float* W[3] = {(const float*)d_in[3], (const float*)d_in[7], (const float*)d_in[11]};
    const float* gam[3] = {(const float*)d_in[5], (const float*)d_in[9], (const float*)d_in[13]};
    const float* bet[3] = {(const float*)d_in[6], (const float*)d_in[10], (const float*)d_in[14]};

    const float* pW1 = (const float*)d_in[15];
    const float* pb1 = (const float*)d_in[16];
    const float* pW2 = (const float*)d_in[17];
    const float* pb2 = (const float*)d_in[18];
    const float* aW1 = (const float*)d_in[19];
    const float* ab1 = (const float*)d_in[20];
    const float* aW2 = (const float*)d_in[21];
    const float* ab2 = (const float*)d_in[22];
    const float* tW1 = (const float*)d_in[23];
    const float* tb1 = (const float*)d_in[24];
    const float* tW2 = (const float*)d_in[25];
    const float* tb2 = (const float*)d_in[26];

    const int C = (E + CHUNK - 1) / CHUNK;   // sort chunks
    const int NB = (N + 127) >> SH;          // coarse buckets (<=1024 for N<=128K)
    const int M = NB * C;

    // ---- workspace carve (256B aligned)
    auto align = [](size_t x) { return (x + 255) & ~(size_t)255; };
    char* w = (char*)d_ws;
    float* dis = (float*)w;      w += align((size_t)N * 4);
    float* bufA = (float*)w;     w += align((size_t)N * 64 * 4);   // fp32 agg
    __half* hp = (__half*)w;     w += align((size_t)N * 64 * 2);   // fp16 messages
    float* st = (float*)w;       w += align(3 * 128 * 4);          // st0,st1,st2
    float* poolsum = (float*)w;  w += align((size_t)G * 64 * 4);
    float* counts = (float*)w;   w += align((size_t)G * 4);
    int* off = (int*)w;          w += align((size_t)(N + 1) * 4);
    int* hist = (int*)w;         w += align((size_t)M * 4);
    int* bsum = (int*)w;         w += align((size_t)SCANB * 4);
    int2* sorted = (int2*)w;     w += align((size_t)E * 8);
    int* eda = (int*)w;          w += align((size_t)E * 4);
    (void)ws_size;

    const int nb_lin = (N + 31) / 32;
    const int nb_ga = 1024;  // grid-stride gather

    // ---- CSR build via bucketed counting sort (parallel scan)
    k_hist<<<C, 256, 0, stream>>>(dst, hist, E, C, NB);
    k_scanA<<<SCANB, 256, 0, stream>>>(hist, bsum, M);
    k_scanB<<<1, 256, 0, stream>>>(bsum);
    k_scanC<<<SCANB, 256, 0, stream>>>(hist, bsum, off, M, E, N);
    k_sort<<<C, 256, 0, stream>>>(src, dst, hist, sorted, E, C, NB);
    k_csr<<<NB, 256, 0, stream>>>(sorted, hist, off, dis, eda, E, C, NB, N);
    k_fill<<<2, 256, 0, stream>>>(st, 0.f, 3 * 128);

    // ---- layer 0 (K=3, no input BN)
    k_linear<3, false><<<nb_lin, 256, 0, stream>>>(x0, W[0], nullptr, nullptr, nullptr, dis, hp, N);
    k_gather<<<nb_ga, 256, 0, stream>>>(off, eda, dis, hp, bufA, st, N);

    // ---- layers 1,2 (K=64, BN of previous layer fused into staging)
    for (int l = 1; l < 3; ++l) {
        k_linear<64, true><<<nb_lin, 256, 0, stream>>>(bufA, W[l], st + (l - 1) * 128,
                                                       gam[l - 1], bet[l - 1], dis, hp, N);
        k_gather<<<nb_ga, 256, 0, stream>>>(off, eda, dis, hp, bufA, st + l * 128, N);
    }

    // ---- global mean pool (BN of layer 2 fused)
    k_fill<<<(G * 64 + 255) / 256, 256, 0, stream>>>(poolsum, 0.f, G * 64);
    k_fill<<<1, 64, 0, stream>>>(counts, 0.f, G);
    const int npw = 32;
    const int nwaves = (N + npw - 1) / npw;
    const int nb_pool = (nwaves * 64 + 255) / 256;
    k_pool<<<nb_pool, 256, 0, stream>>>(bufA, batch, st + 256, gam[2], bet[2],
                                        poolsum, counts, N, npw);

    // ---- heads
    k_heads<<<1, 256, 0, stream>>>(poolsum, counts, pW1, pb1, pW2, pb2,
                                   aW1, ab1, aW2, ab2, tW1, tb1, tW2, tb2,
                                   (float*)d_out, G);
}

// Round 6
// 520.229 us; speedup vs baseline: 4.9620x; 1.2217x over previous
//
#include <hip/hip_runtime.h>
#include <hip/hip_fp16.h>

#define EPSBN 1e-5f
#define SH 7          // bucket = dst >> SH  (128 nodes per bucket)
#define CHUNK 16384   // edges per sort chunk
#define SCANB 256     // scan blocks

// ---------------------------------------------------------------- utilities
__global__ void k_fill(float* __restrict__ p, float v, int n) {
    int i = blockIdx.x * blockDim.x + threadIdx.x;
    if (i < n) p[i] = v;
}

// ------------------------------------------------------- bucketed count sort
// S1: per-chunk histogram over coarse buckets, bucket-major output
__launch_bounds__(1024)
__global__ void k_hist(const int* __restrict__ dst, int* __restrict__ hist,
                       int E, int C, int NB) {
    __shared__ int h[1024];
    const int tid = threadIdx.x, c = blockIdx.x;
    for (int i = tid; i < NB; i += 1024) h[i] = 0;
    __syncthreads();
    const int e0 = c * CHUNK, e1 = min(e0 + CHUNK, E);
    for (int e = e0 + tid; e < e1; e += 1024) atomicAdd(&h[dst[e] >> SH], 1);
    __syncthreads();
    for (int b = tid; b < NB; b += 1024) hist[b * C + c] = h[b];
}

// S2a: per-segment sums
__launch_bounds__(256)
__global__ void k_scanA(const int* __restrict__ hist, int* __restrict__ bsum, int M) {
    __shared__ int part[256];
    const int b = blockIdx.x, t = threadIdx.x;
    const int seg = (M + SCANB - 1) / SCANB;
    const int lo = b * seg, hi = min(lo + seg, M);
    int s = 0;
    for (int i = lo + t; i < hi; i += 256) s += hist[i];
    part[t] = s;
    __syncthreads();
    for (int d = 128; d > 0; d >>= 1) {
        if (t < d) part[t] += part[t + d];
        __syncthreads();
    }
    if (t == 0) bsum[b] = part[0];
}

// S2b: exclusive scan of bsum[SCANB], single block
__launch_bounds__(256)
__global__ void k_scanB(int* __restrict__ bsum) {
    __shared__ int sh[256];
    const int t = threadIdx.x;
    sh[t] = bsum[t];
    __syncthreads();
    for (int d = 1; d < 256; d <<= 1) {
        int v = (t >= d) ? sh[t - d] : 0;
        __syncthreads();
        sh[t] += v;
        __syncthreads();
    }
    bsum[t] = (t == 0) ? 0 : sh[t - 1];
}

// S2c: per-segment exclusive scan (in place) + bsum offset; off[N]=E
__launch_bounds__(256)
__global__ void k_scanC(int* __restrict__ hist, const int* __restrict__ bsum,
                        int* __restrict__ off, int M, int E, int N) {
    __shared__ int part[256];
    const int b = blockIdx.x, t = threadIdx.x;
    const int seg = (M + SCANB - 1) / SCANB;
    const int lo = b * seg, hi = min(lo + seg, M);
    const int per = (seg + 255) >> 8;
    const int tl = lo + t * per, th = min(tl + per, hi);
    int s = 0;
    for (int i = tl; i < th; ++i) s += hist[i];
    part[t] = s;
    __syncthreads();
    for (int d = 1; d < 256; d <<= 1) {
        int v = (t >= d) ? part[t - d] : 0;
        __syncthreads();
        part[t] += v;
        __syncthreads();
    }
    int run = bsum[b] + ((t == 0) ? 0 : part[t - 1]);
    for (int i = tl; i < th; ++i) {
        int v = hist[i];
        hist[i] = run;
        run += v;
    }
    if (b == 0 && t == 0) off[N] = E;
}

// S3: scatter edges into bucket-grouped order (LDS cursors per bucket)
__launch_bounds__(1024)
__global__ void k_sort(const int* __restrict__ src, const int* __restrict__ dst,
                       const int* __restrict__ hist, int2* __restrict__ sorted,
                       int E, int C, int NB) {
    __shared__ int cur[1024];
    const int tid = threadIdx.x, c = blockIdx.x;
    for (int b = tid; b < NB; b += 1024) cur[b] = hist[b * C + c];
    __syncthreads();
    const int e0 = c * CHUNK, e1 = min(e0 + CHUNK, E);
    for (int e = e0 + tid; e < e1; e += 1024) {
        const int d = dst[e];
        const int pos = atomicAdd(&cur[d >> SH], 1);
        sorted[pos] = make_int2(src[e], d);
    }
}

// S4: one block per bucket -> per-node counts, off[], dis[], and final eda
__launch_bounds__(256)
__global__ void k_csr(const int2* __restrict__ sorted, const int* __restrict__ hist,
                      int* __restrict__ off, float* __restrict__ dis,
                      int* __restrict__ eda, int E, int C, int NB, int N) {
    __shared__ int cnt_l[128], scn[128];
    const int tid = threadIdx.x, b = blockIdx.x;
    const int node0 = b << SH;
    const int nloc = min(128, N - node0);
    const int ebeg = hist[b * C];
    const int eend = (b + 1 < NB) ? hist[(b + 1) * C] : E;
    if (tid < 128) cnt_l[tid] = 0;
    __syncthreads();
    for (int e = ebeg + tid; e < eend; e += 256) {
        int2 p = sorted[e];
        atomicAdd(&cnt_l[p.y & 127], 1);
    }
    __syncthreads();
    if (tid < 128) scn[tid] = cnt_l[tid];
    __syncthreads();
    for (int d = 1; d < 128; d <<= 1) {
        int v = 0;
        if (tid < 128 && tid >= d) v = scn[tid - d];
        __syncthreads();
        if (tid < 128) scn[tid] += v;
        __syncthreads();
    }
    if (tid < nloc) {
        const int excl = scn[tid] - cnt_l[tid];
        off[node0 + tid] = ebeg + excl;
        dis[node0 + tid] = rsqrtf((float)cnt_l[tid] + 1.0f);
    }
    __syncthreads();
    if (tid < 128) cnt_l[tid] = scn[tid] - cnt_l[tid];  // reuse as cursor
    __syncthreads();
    for (int e = ebeg + tid; e < eend; e += 256) {
        int2 p = sorted[e];
        const int r = atomicAdd(&cnt_l[p.y & 127], 1);
        eda[ebeg + r] = p.x;
    }
}

// --------------------------------------------------- fused (BN+ReLU) + linear
// hp = (act(X)(N,K) @ W(K,64)) * dis[row]  stored fp16.
template <int K, bool BN>
__launch_bounds__(256)
__global__ void k_linear(const float* __restrict__ X, const float* __restrict__ W,
                         const float* __restrict__ st, const float* __restrict__ g,
                         const float* __restrict__ be, const float* __restrict__ dis,
                         __half* __restrict__ hp, int N) {
    __shared__ float Ws[K * 64];
    __shared__ float Xs[32 * K];
    __shared__ float scs[64], shs[64];
    const int tid = threadIdx.x;
    if (BN && tid < K) {
        const float inv = 1.0f / (float)N;
        const float m = st[tid] * inv;
        const float v = st[64 + tid] * inv - m * m;
        const float sc = g[tid] * rsqrtf(v + EPSBN);
        scs[tid] = sc;
        shs[tid] = fmaf(-m, sc, be[tid]);
    }
    for (int i = tid; i < K * 64; i += 256) Ws[i] = W[i];
    if (BN) __syncthreads();
    const int r0 = blockIdx.x * 32;
    for (int i = tid; i < 32 * K; i += 256) {
        const int r = i / K, c = i - r * K;
        const int row = r0 + r;
        float val = (row < N) ? X[(long)row * K + c] : 0.f;
        if (BN) val = fmaxf(fmaf(val, scs[c], shs[c]), 0.f);
        Xs[i] = val;
    }
    __syncthreads();
    const int c = tid & 63, wv = tid >> 6;
    for (int rr = 0; rr < 8; ++rr) {
        const int r = wv * 8 + rr;
        const int row = r0 + r;
        if (row >= N) break;
        float acc = 0.f;
#pragma unroll
        for (int k = 0; k < K; ++k) acc = fmaf(Xs[r * K + k], Ws[k * 64 + c], acc);
        hp[(long)row * 64 + c] = __float2half(acc * dis[row]);
    }
}

// ------------------------------------------- CSR aggregation + fused BN stats
__launch_bounds__(256)
__global__ void k_gather(const int* __restrict__ off, const int* __restrict__ eda,
                         const float* __restrict__ dis, const __half* __restrict__ hp,
                         float* __restrict__ agg, float* __restrict__ st, int N) {
    __shared__ int els[4][64];
    __shared__ float ls[256], ls2[256];
    const int lane = threadIdx.x & 63;
    const int wv = threadIdx.x >> 6;
    const int nwaves = gridDim.x * 4;
    float s = 0.f, s2 = 0.f;
    for (int w = blockIdx.x * 4 + wv; w < N; w += nwaves) {
        const int e0 = off[w], e1 = off[w + 1];
        float acc0 = __half2float(hp[(long)w * 64 + lane]);
        float acc1 = 0.f, acc2 = 0.f, acc3 = 0.f;
        for (int eb = e0; eb < e1; eb += 64) {
            const int mm = min(64, e1 - eb);
            if (eb + lane < e1) els[wv][lane] = eda[eb + lane];
            int j = 0;
            for (; j + 8 <= mm; j += 8) {
                const int s0 = els[wv][j + 0], s1 = els[wv][j + 1];
                const int s2i = els[wv][j + 2], s3 = els[wv][j + 3];
                const int s4 = els[wv][j + 4], s5 = els[wv][j + 5];
                const int s6 = els[wv][j + 6], s7 = els[wv][j + 7];
                const float v0 = __half2float(hp[(long)s0 * 64 + lane]);
                const float v1 = __half2float(hp[(long)s1 * 64 + lane]);
                const float v2 = __half2float(hp[(long)s2i * 64 + lane]);
                const float v3 = __half2float(hp[(long)s3 * 64 + lane]);
                const float v4 = __half2float(hp[(long)s4 * 64 + lane]);
                const float v5 = __half2float(hp[(long)s5 * 64 + lane]);
                const float v6 = __half2float(hp[(long)s6 * 64 + lane]);
                const float v7 = __half2float(hp[(long)s7 * 64 + lane]);
                acc0 += v0 + v4;
                acc1 += v1 + v5;
                acc2 += v2 + v6;
                acc3 += v3 + v7;
            }
            for (; j < mm; ++j) acc0 += __half2float(hp[(long)els[wv][j] * 64 + lane]);
        }
        const float out = dis[w] * ((acc0 + acc1) + (acc2 + acc3));
        agg[(long)w * 64 + lane] = out;
        s += out;
        s2 = fmaf(out, out, s2);
    }
    ls[threadIdx.x] = s;
    ls2[threadIdx.x] = s2;
    __syncthreads();
    if (threadIdx.x < 64) {
        s = ls[lane] + ls[lane + 64] + ls[lane + 128] + ls[lane + 192];
        s2 = ls2[lane] + ls2[lane + 64] + ls2[lane + 128] + ls2[lane + 192];
        unsafeAtomicAdd(&st[lane], s);
        unsafeAtomicAdd(&st[64 + lane], s2);
    }
}

// ----------------------------------------------------- pooling (fused BN+ReLU)
__launch_bounds__(256)
__global__ void k_pool(const float* __restrict__ x, const int* __restrict__ batch,
                       const float* __restrict__ st, const float* __restrict__ g,
                       const float* __restrict__ be, float* __restrict__ poolsum,
                       float* __restrict__ counts, int N, int npw) {
    const int wid = (blockIdx.x * blockDim.x + threadIdx.x) >> 6;
    const int lane = threadIdx.x & 63;
    const int n0 = wid * npw;
    if (n0 >= N) return;
    const float inv = 1.0f / (float)N;
    const float m = st[lane] * inv;
    const float v = st[64 + lane] * inv - m * m;
    const float sc = g[lane] * rsqrtf(v + EPSBN);
    const float sh = fmaf(-m, sc, be[lane]);
    const int n1 = min(n0 + npw, N);
    float acc = 0.f, cnt = 0.f;
    int gr = batch[n0];
    for (int n = n0; n < n1; ++n) {
        int gn = batch[n];
        if (gn != gr) {
            unsafeAtomicAdd(&poolsum[(long)gr * 64 + lane], acc);
            if (lane == 0) unsafeAtomicAdd(&counts[gr], cnt);
            acc = 0.f;
            cnt = 0.f;
            gr = gn;
        }
        acc += fmaxf(fmaf(x[(long)n * 64 + lane], sc, sh), 0.f);
        cnt += 1.f;
    }
    unsafeAtomicAdd(&poolsum[(long)gr * 64 + lane], acc);
    if (lane == 0) unsafeAtomicAdd(&counts[gr], cnt);
}

// --------------------------------------------------------------------- heads
__launch_bounds__(256)
__global__ void k_heads(const float* __restrict__ poolsum, const float* __restrict__ counts,
                        const float* pW1, const float* pb1, const float* pW2, const float* pb2,
                        const float* aW1, const float* ab1, const float* aW2, const float* ab2,
                        const float* tW1, const float* tb1, const float* tW2, const float* tb2,
                        float* __restrict__ out, int G) {
    __shared__ float P[64 * 64];
    __shared__ float Hd[64 * 32];
    const int tid = threadIdx.x;
    for (int i = tid; i < G * 64; i += 256) {
        int g = i >> 6;
        P[i] = poolsum[i] / fmaxf(counts[g], 1.f);
    }
    __syncthreads();
    for (int j = 0; j < 3; ++j) {
        const float* W1 = (j == 0) ? pW1 : (j == 1) ? aW1 : tW1;
        const float* b1 = (j == 0) ? pb1 : (j == 1) ? ab1 : tb1;
        const float* W2 = (j == 0) ? pW2 : (j == 1) ? aW2 : tW2;
        const float* b2 = (j == 0) ? pb2 : (j == 1) ? ab2 : tb2;
        for (int i = tid; i < G * 32; i += 256) {
            int g = i >> 5, k = i & 31;
            float a = b1[k];
#pragma unroll
            for (int c = 0; c < 64; ++c) a = fmaf(P[g * 64 + c], W1[c * 32 + k], a);
            Hd[i] = fmaxf(a, 0.f);
        }
        __syncthreads();
        const int ow = (j == 2) ? 2 : 1;
        const int off = (j == 2) ? 2 : j;
        for (int i = tid; i < G * ow; i += 256) {
            int g = i / ow, o = i - g * ow;
            float a = b2[o];
#pragma unroll
            for (int k = 0; k < 32; ++k) a = fmaf(Hd[g * 32 + k], W2[k * ow + o], a);
            out[g * 4 + off + o] = a;
        }
        __syncthreads();
    }
}

// ====================================================================== host
extern "C" void kernel_launch(void* const* d_in, const int* in_sizes, int n_in,
                              void* d_out, int out_size, void* d_ws, size_t ws_size,
                              hipStream_t stream) {
    const int N = in_sizes[2];      // batch has N entries
    const int E = in_sizes[1] / 2;  // edge_index is [2, E]
    const int G = out_size / 4;     // output [G, 4]

    const float* x0 = (const float*)d_in[0];
    const int* ei = (const int*)d_in[1];
    const int* src = ei;
    const int* dst = ei + E;
    const int* batch = (const int*)d_in[2];

    const float* W[3] = {(const float*)d_in[3], (const float*)d_in[7], (const float*)d_in[11]};
    const float* gam[3] = {(const float*)d_in[5], (const float*)d_in[9], (const float*)d_in[13]};
    const float* bet[3] = {(const float*)d_in[6], (const float*)d_in[10], (const float*)d_in[14]};

    const float* pW1 = (const float*)d_in[15];
    const float* pb1 = (const float*)d_in[16];
    const float* pW2 = (const float*)d_in[17];
    const float* pb2 = (const float*)d_in[18];
    const float* aW1 = (const float*)d_in[19];
    const float* ab1 = (const float*)d_in[20];
    const float* aW2 = (const float*)d_in[21];
    const float* ab2 = (const float*)d_in[22];
    const float* tW1 = (const float*)d_in[23];
    const float* tb1 = (const float*)d_in[24];
    const float* tW2 = (const float*)d_in[25];
    const float* tb2 = (const float*)d_in[26];

    const int C = (E + CHUNK - 1) / CHUNK;   // sort chunks
    const int NB = (N + 127) >> SH;          // coarse buckets (<=1024 for N<=128K)
    const int M = NB * C;

    // ---- workspace carve (256B aligned)
    auto align = [](size_t x) { return (x + 255) & ~(size_t)255; };
    char* w = (char*)d_ws;
    float* dis = (float*)w;      w += align((size_t)N * 4);
    float* bufA = (float*)w;     w += align((size_t)N * 64 * 4);   // fp32 agg
    __half* hp = (__half*)w;     w += align((size_t)N * 64 * 2);   // fp16 messages
    float* st = (float*)w;       w += align(3 * 128 * 4);          // st0,st1,st2
    float* poolsum = (float*)w;  w += align((size_t)G * 64 * 4);
    float* counts = (float*)w;   w += align((size_t)G * 4);
    int* off = (int*)w;          w += align((size_t)(N + 1) * 4);
    int* hist = (int*)w;         w += align((size_t)M * 4);
    int* bsum = (int*)w;         w += align((size_t)SCANB * 4);
    int2* sorted = (int2*)w;     w += align((size_t)E * 8);
    int* eda = (int*)w;          w += align((size_t)E * 4);
    (void)ws_size;

    const int nb_lin = (N + 31) / 32;
    const int nb_ga = 2048;  // grid-stride gather (100% occupancy target)

    // ---- CSR build via bucketed counting sort (parallel scan)
    k_hist<<<C, 1024, 0, stream>>>(dst, hist, E, C, NB);
    k_scanA<<<SCANB, 256, 0, stream>>>(hist, bsum, M);
    k_scanB<<<1, 256, 0, stream>>>(bsum);
    k_scanC<<<SCANB, 256, 0, stream>>>(hist, bsum, off, M, E, N);
    k_sort<<<C, 1024, 0, stream>>>(src, dst, hist, sorted, E, C, NB);
    k_csr<<<NB, 256, 0, stream>>>(sorted, hist, off, dis, eda, E, C, NB, N);
    k_fill<<<2, 256, 0, stream>>>(st, 0.f, 3 * 128);

    // ---- layer 0 (K=3, no input BN)
    k_linear<3, false><<<nb_lin, 256, 0, stream>>>(x0, W[0], nullptr, nullptr, nullptr, dis, hp, N);
    k_gather<<<nb_ga, 256, 0, stream>>>(off, eda, dis, hp, bufA, st, N);

    // ---- layers 1,2 (K=64, BN of previous layer fused into staging)
    for (int l = 1; l < 3; ++l) {
        k_linear<64, true><<<nb_lin, 256, 0, stream>>>(bufA, W[l], st + (l - 1) * 128,
                                                       gam[l - 1], bet[l - 1], dis, hp, N);
        k_gather<<<nb_ga, 256, 0, stream>>>(off, eda, dis, hp, bufA, st + l * 128, N);
    }

    // ---- global mean pool (BN of layer 2 fused)
    k_fill<<<(G * 64 + 255) / 256, 256, 0, stream>>>(poolsum, 0.f, G * 64);
    k_fill<<<1, 64, 0, stream>>>(counts, 0.f, G);
    const int npw = 32;
    const int nwaves = (N + npw - 1) / npw;
    const int nb_pool = (nwaves * 64 + 255) / 256;
    k_pool<<<nb_pool, 256, 0, stream>>>(bufA, batch, st + 256, gam[2], bet[2],
                                        poolsum, counts, N, npw);

    // ---- heads
    k_heads<<<1, 256, 0, stream>>>(poolsum, counts, pW1, pb1, pW2, pb2,
                                   aW1, ab1, aW2, ab2, tW1, tb1, tW2, tb2,
                                   (float*)d_out, G);
}